// Round 9
// baseline (164.214 us; speedup 1.0000x reference)
//
#include <hip/hip_runtime.h>

// Problem constants
#define BATCH   32
#define CIN     256
#define COUT    64
#define HW      1024          // 32*32
#define NE      1024          // codebook size
#define ED      64            // code dim
#define ZTOT    2097152       // BATCH*COUT*HW

// d_out layout (floats): z_q_st[ZTOT], loss[1], sampled[32768], min_idx[32768]
#define OFF_LOSS 2097152
#define OFF_SAMP 2097153
#define OFF_IDX  2129921

// LDS strides (floats). k-major, stride%32==4: measured conflict-free (R0/R1).
#define CXSTR 68    // conv Xs/Ws [64 c][64 + 4]
#define XSTR  68    // dist zs [64 k][64 row + 4]
#define ESTR  132   // dist es [64 k][128 code + 4]

// ---------------------------------------------------------------------------
// k_pre: conv blocks FIRST, then zero/norms. Conv now uses T14 async-stage:
// issue next c0-chunk's x/w loads into regs BEFORE the FMA loop, ds_write
// after the barrier -> HBM loads stay in flight under compute (was: 78% HBM
// duty, staging latency serialized between barriers).
// blocks 0..511   : conv, 64-px tile (4px x 4o per thread)
// blocks 512..639 : zero out_samp
// blocks 640..655 : contrast partials (block-local inv-norms)
// blocks 656..659 : enorm
__global__ __launch_bounds__(256, 4) void k_pre(const float* __restrict__ x,
                                                const float* __restrict__ w,
                                                const float* __restrict__ bias,
                                                float* __restrict__ z,
                                                const float* __restrict__ emb,
                                                float* __restrict__ out_samp,
                                                float* __restrict__ enorm,
                                                float* __restrict__ cpart) {
    __shared__ float SH[64 * CXSTR * 2];    // 34.8 KB, aliased per branch
    int bx = blockIdx.x;
    int t  = threadIdx.x;

    if (bx < 512) {                       // ---- conv (T14 async-stage)
        float* Xs = SH;                   // [64 c][CXSTR]
        float* Ws = SH + 64 * CXSTR;      // [64 c][CXSTR]
        int b  = bx >> 4;                 // 0..31
        int p0 = (bx & 15) * 64;          // 0..960
        int pg = t & 15;                  // px: 4*pg + i
        int og = t >> 4;                  // o : 4*og + j
        int u  = t & 15, cg2 = t >> 4;    // staging coords
        float acc[4][4];
        #pragma unroll
        for (int i = 0; i < 4; i++)
            #pragma unroll
            for (int j = 0; j < 4; j++) acc[i][j] = 0.0f;

        // prologue: issue chunk-0 loads into regs
        float4 xst[4], wst[4];
        #pragma unroll
        for (int m = 0; m < 4; m++) {
            int c = cg2 + 16 * m;
            xst[m] = *(const float4*)&x[(size_t)(b * CIN + c) * HW + p0 + 4 * u];
            wst[m] = *(const float4*)&w[c * CIN + 4 * u];   // o == c index form
        }

        for (int c0 = 0; c0 < CIN; c0 += 64) {
            __syncthreads();              // prior compute done reading Xs/Ws
            #pragma unroll
            for (int m = 0; m < 4; m++) {
                int c = cg2 + 16 * m;
                *(float4*)&Xs[c * CXSTR + 4 * u] = xst[m];
                Ws[(4 * u + 0) * CXSTR + c] = wst[m].x;
                Ws[(4 * u + 1) * CXSTR + c] = wst[m].y;
                Ws[(4 * u + 2) * CXSTR + c] = wst[m].z;
                Ws[(4 * u + 3) * CXSTR + c] = wst[m].w;
            }
            __syncthreads();              // tiles ready
            if (c0 < CIN - 64) {          // issue NEXT chunk's loads now
                int c0n = c0 + 64;
                #pragma unroll
                for (int m = 0; m < 4; m++) {
                    int c = cg2 + 16 * m;
                    xst[m] = *(const float4*)&x[(size_t)(b * CIN + c0n + c) * HW + p0 + 4 * u];
                    wst[m] = *(const float4*)&w[c * CIN + c0n + 4 * u];
                }
            }
            #pragma unroll 8
            for (int k = 0; k < 64; k++) {
                float4 xv = *(const float4*)&Xs[k * CXSTR + 4 * pg];
                float4 wv = *(const float4*)&Ws[k * CXSTR + 4 * og];
                float xa[4] = {xv.x, xv.y, xv.z, xv.w};
                float wb[4] = {wv.x, wv.y, wv.z, wv.w};
                #pragma unroll
                for (int i = 0; i < 4; i++)
                    #pragma unroll
                    for (int j = 0; j < 4; j++)
                        acc[i][j] = fmaf(xa[i], wb[j], acc[i][j]);
            }
        }
        #pragma unroll
        for (int j = 0; j < 4; j++) {
            int o = 4 * og + j;
            float bv = bias[o];
            float4 out;
            out.x = acc[0][j] + bv;
            out.y = acc[1][j] + bv;
            out.z = acc[2][j] + bv;
            out.w = acc[3][j] + bv;
            *(float4*)&z[(size_t)(b * COUT + o) * HW + p0 + 4 * pg] = out;
        }
        return;
    }
    if (bx < 640) {                       // ---- zero sampled
        out_samp[(bx - 512) * 256 + t] = 0.0f;
        return;
    }
    if (bx < 656) {                       // ---- contrast partial (16 blocks)
        float* invl = SH;                 // [64]
        float* S    = SH + 64;            // [256]
        int b2 = bx - 640;
        int i0 = b2 * 64;
        if (t < 64) {
            const float* e = emb + (size_t)(i0 + t) * ED;
            float r8[8];
            #pragma unroll
            for (int s = 0; s < 8; s++) { float xx = e[s]; r8[s] = xx * xx; }
            #pragma unroll
            for (int m = 1; m < 8; m++) {
                #pragma unroll
                for (int s = 0; s < 8; s++) { float xx = e[8 * m + s]; r8[s] += xx * xx; }
            }
            float en = ((r8[0] + r8[1]) + (r8[2] + r8[3])) + ((r8[4] + r8[5]) + (r8[6] + r8[7]));
            invl[t] = 1.0f / sqrtf(en);
        }
        __syncthreads();
        int d = t & 63, q = t >> 6;
        float s = 0.0f;
        #pragma unroll
        for (int m = 0; m < 16; m++) {
            int il = q + 4 * m;
            s = fmaf(emb[(size_t)(i0 + il) * ED + d], invl[il], s);
        }
        S[t] = s;
        __syncthreads();
        if (t < 64)
            cpart[b2 * 64 + t] = (S[t] + S[t + 64]) + (S[t + 128] + S[t + 192]);
        return;
    }
    {                                     // ---- enorm (4 blocks: 656..659)
        int j = (bx - 656) * 256 + t;     // 0..1023
        const float* e = emb + (size_t)j * ED;
        float r8[8];
        #pragma unroll
        for (int s = 0; s < 8; s++) { float xx = e[s]; r8[s] = xx * xx; }
        #pragma unroll
        for (int m = 1; m < 8; m++) {
            #pragma unroll
            for (int s = 0; s < 8; s++) { float xx = e[8 * m + s]; r8[s] += xx * xx; }
        }
        enorm[j] = ((r8[0] + r8[1]) + (r8[2] + r8[3])) + ((r8[4] + r8[5]) + (r8[6] + r8[7]));
    }
}

// ---------------------------------------------------------------------------
// k_dist: R0's proven loop with ONE change (T14 async-stage): each chunk's
// 32 emb scalar loads are issued into registers right after the es-ready
// barrier (i.e. BEFORE the FMA loop of the current chunk) and ds_written
// after the next release barrier. Loads/stores reordered only -- every fmaf
// chain, barrier count, layout and argmin path identical -> bit-exact.
// NO threadfence (R7: device-scope release fence cost ~17 us).
__global__ __launch_bounds__(256, 2) void k_dist(const float* __restrict__ z,
                                                 const float* __restrict__ emb,
                                                 const float* __restrict__ enorm,
                                                 float* __restrict__ out_idx,
                                                 float* __restrict__ out_samp,
                                                 float* __restrict__ out_zq,
                                                 float* __restrict__ ssep) {
    __shared__ float zs[64 * XSTR];      // [k][row] transposed
    __shared__ float es[64 * ESTR];      // [k][code_local]
    __shared__ float zn_s[64];
    __shared__ float en_s[128];
    __shared__ float redd_s[16 * 64];
    __shared__ int   redj_s[16 * 64];
    __shared__ int   bj_s[64];
    __shared__ float warr[4];
    int t = threadIdx.x;
    int row0 = blockIdx.x * 64;
    int rg = t & 15;     // rows  4*rg + i
    int cg = t >> 4;     // codes 8*cg + j (local)
    int sk = t & 63, swv = t >> 6;       // staging coords

    // stage zs transposed: zs[k][r]
    {
        #pragma unroll
        for (int m = 0; m < 4; m++) {
            int v = swv + 4 * m;         // 0..15
            float4 val;
            val.x = z[(size_t)(row0 + 4 * v + 0) * ED + sk];
            val.y = z[(size_t)(row0 + 4 * v + 1) * ED + sk];
            val.z = z[(size_t)(row0 + 4 * v + 2) * ED + sk];
            val.w = z[(size_t)(row0 + 4 * v + 3) * ED + sk];
            *(float4*)&zs[sk * XSTR + 4 * v] = val;
        }
    }
    // zn: numpy-pairwise sum of squares per row
    if (t < 64) {
        const float* zr = z + (size_t)(row0 + t) * ED;
        float r8[8];
        #pragma unroll
        for (int s = 0; s < 8; s++) { float xx = zr[s]; r8[s] = xx * xx; }
        #pragma unroll
        for (int m = 1; m < 8; m++) {
            #pragma unroll
            for (int s = 0; s < 8; s++) { float xx = zr[8 * m + s]; r8[s] += xx * xx; }
        }
        zn_s[t] = ((r8[0] + r8[1]) + (r8[2] + r8[3])) + ((r8[4] + r8[5]) + (r8[6] + r8[7]));
    }

    // T14 prologue: issue chunk-0 emb loads into registers
    float st[32];
    float4 enr;
    #pragma unroll
    for (int m = 0; m < 8; m++) {
        int v = swv + 4 * m;             // 0..31
        st[4 * m + 0] = emb[(size_t)(4 * v + 0) * ED + sk];
        st[4 * m + 1] = emb[(size_t)(4 * v + 1) * ED + sk];
        st[4 * m + 2] = emb[(size_t)(4 * v + 2) * ED + sk];
        st[4 * m + 3] = emb[(size_t)(4 * v + 3) * ED + sk];
    }
    if (t < 32) enr = *(const float4*)&enorm[4 * t];

    float bestd[4];
    int   bestj[4];
    #pragma unroll
    for (int i = 0; i < 4; i++) { bestd[i] = __builtin_huge_valf(); bestj[i] = 0; }

    for (int ch = 0; ch < 8; ch++) {
        int c0 = ch * 128;
        __syncthreads();   // prior chunk's compute done reading es/en_s
        {
            #pragma unroll
            for (int m = 0; m < 8; m++) {
                int v = swv + 4 * m;     // 0..31
                float4 val;
                val.x = st[4 * m + 0];
                val.y = st[4 * m + 1];
                val.z = st[4 * m + 2];
                val.w = st[4 * m + 3];
                *(float4*)&es[sk * ESTR + 4 * v] = val;
            }
            if (t < 32) *(float4*)&en_s[4 * t] = enr;
        }
        __syncthreads();   // es ready

        if (ch < 7) {      // issue NEXT chunk's loads before computing
            int c0n = c0 + 128;
            #pragma unroll
            for (int m = 0; m < 8; m++) {
                int v = swv + 4 * m;
                st[4 * m + 0] = emb[(size_t)(c0n + 4 * v + 0) * ED + sk];
                st[4 * m + 1] = emb[(size_t)(c0n + 4 * v + 1) * ED + sk];
                st[4 * m + 2] = emb[(size_t)(c0n + 4 * v + 2) * ED + sk];
                st[4 * m + 3] = emb[(size_t)(c0n + 4 * v + 3) * ED + sk];
            }
            if (t < 32) enr = *(const float4*)&enorm[c0n + 4 * t];
        }

        float acc[4][8];
        #pragma unroll
        for (int i = 0; i < 4; i++)
            #pragma unroll
            for (int j = 0; j < 8; j++) acc[i][j] = 0.0f;

        #pragma unroll 8
        for (int k = 0; k < 64; k++) {
            float4 xv = *(const float4*)&zs[k * XSTR + 4 * rg];
            float4 e0 = *(const float4*)&es[k * ESTR + 8 * cg];
            float4 e1 = *(const float4*)&es[k * ESTR + 8 * cg + 4];
            float xa[4] = {xv.x, xv.y, xv.z, xv.w};
            float eb[8] = {e0.x, e0.y, e0.z, e0.w, e1.x, e1.y, e1.z, e1.w};
            #pragma unroll
            for (int i = 0; i < 4; i++)
                #pragma unroll
                for (int j = 0; j < 8; j++)
                    acc[i][j] = fmaf(xa[i], eb[j], acc[i][j]);
        }

        // epilogue: d = fl(fl(zn + en) - 2*dot); strict < keeps first index
        #pragma unroll
        for (int i = 0; i < 4; i++) {
            float zn = zn_s[4 * rg + i];
            #pragma unroll
            for (int j = 0; j < 8; j++) {
                int cl = 8 * cg + j;
                float A = zn + en_s[cl];
                float D = A - 2.0f * acc[i][j];
                if (D < bestd[i]) { bestd[i] = D; bestj[i] = c0 + cl; }
            }
        }
    }

    #pragma unroll
    for (int i = 0; i < 4; i++) {
        redd_s[cg * 64 + 4 * rg + i] = bestd[i];
        redj_s[cg * 64 + 4 * rg + i] = bestj[i];
    }
    __syncthreads();
    if (t < 64) {
        float bd = __builtin_huge_valf();
        int   bj = 0x7fffffff;
        #pragma unroll
        for (int c = 0; c < 16; c++) {
            float dd = redd_s[c * 64 + t];
            int   jj = redj_s[c * 64 + t];
            if (dd < bd || (dd == bd && jj < bj)) { bd = dd; bj = jj; }
        }
        int rowg = row0 + t;
        bj_s[t]       = bj;
        out_idx[rowg] = (float)bj;              // min_idx as float
        atomicExch(&out_samp[bj], 1.0f);        // scattered, low contention
    }
    __syncthreads();

    // Fused STE epilogue: z from zs (bit-exact), emb gather, SSE partial.
    // thread t: row r = t&63, k-range [16*kq, 16*kq+16)
    {
        int r  = t & 63;
        int kq = t >> 6;
        int bj = bj_s[r];
        const float* er = emb + (size_t)bj * ED + kq * 16;
        float sq = 0.0f;
        #pragma unroll
        for (int m = 0; m < 4; m++) {
            float4 ev = *(const float4*)&er[4 * m];
            float zv0 = zs[(kq * 16 + 4 * m + 0) * XSTR + r];
            float zv1 = zs[(kq * 16 + 4 * m + 1) * XSTR + r];
            float zv2 = zs[(kq * 16 + 4 * m + 2) * XSTR + r];
            float zv3 = zs[(kq * 16 + 4 * m + 3) * XSTR + r];
            float d0 = ev.x - zv0, d1 = ev.y - zv1, d2 = ev.z - zv2, d3 = ev.w - zv3;
            float4 o4;
            o4.x = zv0 + d0; o4.y = zv1 + d1; o4.z = zv2 + d2; o4.w = zv3 + d3;
            *(float4*)&out_zq[(size_t)(row0 + r) * ED + kq * 16 + 4 * m] = o4;
            sq += d0 * d0; sq += d1 * d1; sq += d2 * d2; sq += d3 * d3;
        }
        #pragma unroll
        for (int off = 32; off > 0; off >>= 1) sq += __shfl_down(sq, off, 64);
        int lane = t & 63, wv2 = t >> 6;
        if (lane == 0) warr[wv2] = sq;
    }
    __syncthreads();
    if (t == 0)
        ssep[blockIdx.x] = (warr[0] + warr[1]) + (warr[2] + warr[3]);
}

// ---------------------------------------------------------------------------
// k_final (R0 verbatim): deterministic combine of 512 SSE partials (double
// tree) and the 16x64 contrastive partials; writes the loss scalar.
__global__ __launch_bounds__(256) void k_final(const float* __restrict__ ssep,
                                               const float* __restrict__ cpart,
                                               float* __restrict__ out_loss) {
    __shared__ double SD[256];
    __shared__ float  CS;
    int t = threadIdx.x;
    SD[t] = (double)ssep[t] + (double)ssep[t + 256];
    __syncthreads();
    #pragma unroll
    for (int off = 128; off > 0; off >>= 1) {
        if (t < off) SD[t] += SD[t + off];
        __syncthreads();
    }
    if (t < 64) {
        float v = 0.0f;
        #pragma unroll
        for (int m = 0; m < 16; m++) v += cpart[m * 64 + t];
        float sq = v * v;
        #pragma unroll
        for (int off = 32; off > 0; off >>= 1) sq += __shfl_down(sq, off, 64);
        if (t == 0) CS = sq / (1024.0f * 1024.0f);
    }
    __syncthreads();
    if (t == 0) {
        float m = (float)(SD[0] / (double)ZTOT);
        float loss = m + 0.25f * m;         // LEGACY: mse + BETA*mse
        out_loss[0] = loss + CS;
    }
}

// ---------------------------------------------------------------------------
extern "C" void kernel_launch(void* const* d_in, const int* in_sizes, int n_in,
                              void* d_out, int out_size, void* d_ws, size_t ws_size,
                              hipStream_t stream) {
    (void)in_sizes; (void)n_in; (void)out_size; (void)ws_size;
    const float* z_     = (const float*)d_in[0];
    const float* conv_w = (const float*)d_in[1];
    const float* conv_b = (const float*)d_in[2];
    const float* emb    = (const float*)d_in[3];

    float* out      = (float*)d_out;
    float* out_zq   = out;
    float* out_loss = out + OFF_LOSS;
    float* out_samp = out + OFF_SAMP;
    float* out_idx  = out + OFF_IDX;

    char*  ws       = (char*)d_ws;
    float* wz       = (float*)ws;                         // 2M floats (8 MB)
    float* enorm    = (float*)(ws + 8388608);             // 1024 floats
    float* cpart    = (float*)(ws + 8392704);             // 16*64 floats
    float* ssep     = (float*)(ws + 8396800);             // 512 floats

    k_pre  <<<660, 256, 0, stream>>>(z_, conv_w, conv_b, wz, emb, out_samp, enorm, cpart);
    k_dist <<<512, 256, 0, stream>>>(wz, emb, enorm, out_idx, out_samp, out_zq, ssep);
    k_final<<<1,   256, 0, stream>>>(ssep, cpart, out_loss);
}

// Round 10
// 163.425 us; speedup vs baseline: 1.0048x; 1.0048x over previous
//
#include <hip/hip_runtime.h>

// Problem constants
#define BATCH   32
#define CIN     256
#define COUT    64
#define HW      1024          // 32*32
#define NE      1024          // codebook size
#define ED      64            // code dim
#define ZTOT    2097152       // BATCH*COUT*HW

// d_out layout (floats): z_q_st[ZTOT], loss[1], sampled[32768], min_idx[32768]
#define OFF_LOSS 2097152
#define OFF_SAMP 2097153
#define OFF_IDX  2129921

// LDS strides (floats). k-major, stride%32==4: measured conflict-free (R0/R1).
#define CXSTR 68    // conv Xs/Ws [64 c][64 + 4]
#define XSTR  68    // dist zs [64 k][64 row + 4]
#define ESTR  132   // dist es [64 k][128 code + 4]

// ---------------------------------------------------------------------------
// k_pre (R8 verbatim -- R9's conv T14 prefetch REGRESSED ~7 us: at
// __launch_bounds__(256,4) the 128-VGPR budget has no room for +32 prefetch
// regs; k_dist at (256,2) does. Conv stays plain).
// blocks 0..511   : conv, 64-px tile (4px x 4o per thread)
// blocks 512..639 : zero out_samp
// blocks 640..655 : contrast partials (block-local inv-norms)
// blocks 656..659 : enorm
__global__ __launch_bounds__(256, 4) void k_pre(const float* __restrict__ x,
                                                const float* __restrict__ w,
                                                const float* __restrict__ bias,
                                                float* __restrict__ z,
                                                const float* __restrict__ emb,
                                                float* __restrict__ out_samp,
                                                float* __restrict__ enorm,
                                                float* __restrict__ cpart) {
    __shared__ float SH[64 * CXSTR * 2];    // 34.8 KB, aliased per branch
    int bx = blockIdx.x;
    int t  = threadIdx.x;

    if (bx < 512) {                       // ---- conv (R1-proven tiling)
        float* Xs = SH;                   // [64 c][CXSTR]
        float* Ws = SH + 64 * CXSTR;      // [64 c][CXSTR]
        int b  = bx >> 4;                 // 0..31
        int p0 = (bx & 15) * 64;          // 0..960
        int pg = t & 15;                  // px: 4*pg + i
        int og = t >> 4;                  // o : 4*og + j
        float acc[4][4];
        #pragma unroll
        for (int i = 0; i < 4; i++)
            #pragma unroll
            for (int j = 0; j < 4; j++) acc[i][j] = 0.0f;

        for (int c0 = 0; c0 < CIN; c0 += 64) {
            __syncthreads();
            {
                int u = t & 15, cg2 = t >> 4;
                #pragma unroll
                for (int m = 0; m < 4; m++) {
                    int c = cg2 + 16 * m;
                    float4 v = *(const float4*)&x[(size_t)(b * CIN + c0 + c) * HW + p0 + 4 * u];
                    *(float4*)&Xs[c * CXSTR + 4 * u] = v;
                }
                #pragma unroll
                for (int m = 0; m < 4; m++) {
                    int o = cg2 + 16 * m;
                    float4 v = *(const float4*)&w[o * CIN + c0 + 4 * u];
                    Ws[(4 * u + 0) * CXSTR + o] = v.x;
                    Ws[(4 * u + 1) * CXSTR + o] = v.y;
                    Ws[(4 * u + 2) * CXSTR + o] = v.z;
                    Ws[(4 * u + 3) * CXSTR + o] = v.w;
                }
            }
            __syncthreads();
            #pragma unroll 8
            for (int k = 0; k < 64; k++) {
                float4 xv = *(const float4*)&Xs[k * CXSTR + 4 * pg];
                float4 wv = *(const float4*)&Ws[k * CXSTR + 4 * og];
                float xa[4] = {xv.x, xv.y, xv.z, xv.w};
                float wb[4] = {wv.x, wv.y, wv.z, wv.w};
                #pragma unroll
                for (int i = 0; i < 4; i++)
                    #pragma unroll
                    for (int j = 0; j < 4; j++)
                        acc[i][j] = fmaf(xa[i], wb[j], acc[i][j]);
            }
        }
        #pragma unroll
        for (int j = 0; j < 4; j++) {
            int o = 4 * og + j;
            float bv = bias[o];
            float4 out;
            out.x = acc[0][j] + bv;
            out.y = acc[1][j] + bv;
            out.z = acc[2][j] + bv;
            out.w = acc[3][j] + bv;
            *(float4*)&z[(size_t)(b * COUT + o) * HW + p0 + 4 * pg] = out;
        }
        return;
    }
    if (bx < 640) {                       // ---- zero sampled
        out_samp[(bx - 512) * 256 + t] = 0.0f;
        return;
    }
    if (bx < 656) {                       // ---- contrast partial (16 blocks)
        float* invl = SH;                 // [64]
        float* S    = SH + 64;            // [256]
        int b2 = bx - 640;
        int i0 = b2 * 64;
        if (t < 64) {
            const float* e = emb + (size_t)(i0 + t) * ED;
            float r8[8];
            #pragma unroll
            for (int s = 0; s < 8; s++) { float xx = e[s]; r8[s] = xx * xx; }
            #pragma unroll
            for (int m = 1; m < 8; m++) {
                #pragma unroll
                for (int s = 0; s < 8; s++) { float xx = e[8 * m + s]; r8[s] += xx * xx; }
            }
            float en = ((r8[0] + r8[1]) + (r8[2] + r8[3])) + ((r8[4] + r8[5]) + (r8[6] + r8[7]));
            invl[t] = 1.0f / sqrtf(en);
        }
        __syncthreads();
        int d = t & 63, q = t >> 6;
        float s = 0.0f;
        #pragma unroll
        for (int m = 0; m < 16; m++) {
            int il = q + 4 * m;
            s = fmaf(emb[(size_t)(i0 + il) * ED + d], invl[il], s);
        }
        S[t] = s;
        __syncthreads();
        if (t < 64)
            cpart[b2 * 64 + t] = (S[t] + S[t + 64]) + (S[t + 128] + S[t + 192]);
        return;
    }
    {                                     // ---- enorm (4 blocks: 656..659)
        int j = (bx - 656) * 256 + t;     // 0..1023
        const float* e = emb + (size_t)j * ED;
        float r8[8];
        #pragma unroll
        for (int s = 0; s < 8; s++) { float xx = e[s]; r8[s] = xx * xx; }
        #pragma unroll
        for (int m = 1; m < 8; m++) {
            #pragma unroll
            for (int s = 0; s < 8; s++) { float xx = e[8 * m + s]; r8[s] += xx * xx; }
        }
        enorm[j] = ((r8[0] + r8[1]) + (r8[2] + r8[3])) + ((r8[4] + r8[5]) + (r8[6] + r8[7]));
    }
}

// ---------------------------------------------------------------------------
// k_dist (R9 verbatim, best measured 71.9 us): R0's loop + T14 async-stage
// (next chunk's emb loads issued into regs before the FMA loop, ds_written
// after the release barrier). VGPR 128, no spill at (256,2). Bit-exact.
// NO threadfence (R7: device-scope release fence cost ~17 us).
__global__ __launch_bounds__(256, 2) void k_dist(const float* __restrict__ z,
                                                 const float* __restrict__ emb,
                                                 const float* __restrict__ enorm,
                                                 float* __restrict__ out_idx,
                                                 float* __restrict__ out_samp,
                                                 float* __restrict__ out_zq,
                                                 float* __restrict__ ssep) {
    __shared__ float zs[64 * XSTR];      // [k][row] transposed
    __shared__ float es[64 * ESTR];      // [k][code_local]
    __shared__ float zn_s[64];
    __shared__ float en_s[128];
    __shared__ float redd_s[16 * 64];
    __shared__ int   redj_s[16 * 64];
    __shared__ int   bj_s[64];
    __shared__ float warr[4];
    int t = threadIdx.x;
    int row0 = blockIdx.x * 64;
    int rg = t & 15;     // rows  4*rg + i
    int cg = t >> 4;     // codes 8*cg + j (local)
    int sk = t & 63, swv = t >> 6;       // staging coords

    // stage zs transposed: zs[k][r]
    {
        #pragma unroll
        for (int m = 0; m < 4; m++) {
            int v = swv + 4 * m;         // 0..15
            float4 val;
            val.x = z[(size_t)(row0 + 4 * v + 0) * ED + sk];
            val.y = z[(size_t)(row0 + 4 * v + 1) * ED + sk];
            val.z = z[(size_t)(row0 + 4 * v + 2) * ED + sk];
            val.w = z[(size_t)(row0 + 4 * v + 3) * ED + sk];
            *(float4*)&zs[sk * XSTR + 4 * v] = val;
        }
    }
    // zn: numpy-pairwise sum of squares per row
    if (t < 64) {
        const float* zr = z + (size_t)(row0 + t) * ED;
        float r8[8];
        #pragma unroll
        for (int s = 0; s < 8; s++) { float xx = zr[s]; r8[s] = xx * xx; }
        #pragma unroll
        for (int m = 1; m < 8; m++) {
            #pragma unroll
            for (int s = 0; s < 8; s++) { float xx = zr[8 * m + s]; r8[s] += xx * xx; }
        }
        zn_s[t] = ((r8[0] + r8[1]) + (r8[2] + r8[3])) + ((r8[4] + r8[5]) + (r8[6] + r8[7]));
    }

    // T14 prologue: issue chunk-0 emb loads into registers
    float st[32];
    float4 enr;
    #pragma unroll
    for (int m = 0; m < 8; m++) {
        int v = swv + 4 * m;             // 0..31
        st[4 * m + 0] = emb[(size_t)(4 * v + 0) * ED + sk];
        st[4 * m + 1] = emb[(size_t)(4 * v + 1) * ED + sk];
        st[4 * m + 2] = emb[(size_t)(4 * v + 2) * ED + sk];
        st[4 * m + 3] = emb[(size_t)(4 * v + 3) * ED + sk];
    }
    if (t < 32) enr = *(const float4*)&enorm[4 * t];

    float bestd[4];
    int   bestj[4];
    #pragma unroll
    for (int i = 0; i < 4; i++) { bestd[i] = __builtin_huge_valf(); bestj[i] = 0; }

    for (int ch = 0; ch < 8; ch++) {
        int c0 = ch * 128;
        __syncthreads();   // prior chunk's compute done reading es/en_s
        {
            #pragma unroll
            for (int m = 0; m < 8; m++) {
                int v = swv + 4 * m;     // 0..31
                float4 val;
                val.x = st[4 * m + 0];
                val.y = st[4 * m + 1];
                val.z = st[4 * m + 2];
                val.w = st[4 * m + 3];
                *(float4*)&es[sk * ESTR + 4 * v] = val;
            }
            if (t < 32) *(float4*)&en_s[4 * t] = enr;
        }
        __syncthreads();   // es ready

        if (ch < 7) {      // issue NEXT chunk's loads before computing
            int c0n = c0 + 128;
            #pragma unroll
            for (int m = 0; m < 8; m++) {
                int v = swv + 4 * m;
                st[4 * m + 0] = emb[(size_t)(c0n + 4 * v + 0) * ED + sk];
                st[4 * m + 1] = emb[(size_t)(c0n + 4 * v + 1) * ED + sk];
                st[4 * m + 2] = emb[(size_t)(c0n + 4 * v + 2) * ED + sk];
                st[4 * m + 3] = emb[(size_t)(c0n + 4 * v + 3) * ED + sk];
            }
            if (t < 32) enr = *(const float4*)&enorm[c0n + 4 * t];
        }

        float acc[4][8];
        #pragma unroll
        for (int i = 0; i < 4; i++)
            #pragma unroll
            for (int j = 0; j < 8; j++) acc[i][j] = 0.0f;

        #pragma unroll 8
        for (int k = 0; k < 64; k++) {
            float4 xv = *(const float4*)&zs[k * XSTR + 4 * rg];
            float4 e0 = *(const float4*)&es[k * ESTR + 8 * cg];
            float4 e1 = *(const float4*)&es[k * ESTR + 8 * cg + 4];
            float xa[4] = {xv.x, xv.y, xv.z, xv.w};
            float eb[8] = {e0.x, e0.y, e0.z, e0.w, e1.x, e1.y, e1.z, e1.w};
            #pragma unroll
            for (int i = 0; i < 4; i++)
                #pragma unroll
                for (int j = 0; j < 8; j++)
                    acc[i][j] = fmaf(xa[i], eb[j], acc[i][j]);
        }

        // epilogue: d = fl(fl(zn + en) - 2*dot); strict < keeps first index
        #pragma unroll
        for (int i = 0; i < 4; i++) {
            float zn = zn_s[4 * rg + i];
            #pragma unroll
            for (int j = 0; j < 8; j++) {
                int cl = 8 * cg + j;
                float A = zn + en_s[cl];
                float D = A - 2.0f * acc[i][j];
                if (D < bestd[i]) { bestd[i] = D; bestj[i] = c0 + cl; }
            }
        }
    }

    #pragma unroll
    for (int i = 0; i < 4; i++) {
        redd_s[cg * 64 + 4 * rg + i] = bestd[i];
        redj_s[cg * 64 + 4 * rg + i] = bestj[i];
    }
    __syncthreads();
    if (t < 64) {
        float bd = __builtin_huge_valf();
        int   bj = 0x7fffffff;
        #pragma unroll
        for (int c = 0; c < 16; c++) {
            float dd = redd_s[c * 64 + t];
            int   jj = redj_s[c * 64 + t];
            if (dd < bd || (dd == bd && jj < bj)) { bd = dd; bj = jj; }
        }
        int rowg = row0 + t;
        bj_s[t]       = bj;
        out_idx[rowg] = (float)bj;              // min_idx as float
        atomicExch(&out_samp[bj], 1.0f);        // scattered, low contention
    }
    __syncthreads();

    // Fused STE epilogue: z from zs (bit-exact), emb gather, SSE partial.
    // thread t: row r = t&63, k-range [16*kq, 16*kq+16)
    {
        int r  = t & 63;
        int kq = t >> 6;
        int bj = bj_s[r];
        const float* er = emb + (size_t)bj * ED + kq * 16;
        float sq = 0.0f;
        #pragma unroll
        for (int m = 0; m < 4; m++) {
            float4 ev = *(const float4*)&er[4 * m];
            float zv0 = zs[(kq * 16 + 4 * m + 0) * XSTR + r];
            float zv1 = zs[(kq * 16 + 4 * m + 1) * XSTR + r];
            float zv2 = zs[(kq * 16 + 4 * m + 2) * XSTR + r];
            float zv3 = zs[(kq * 16 + 4 * m + 3) * XSTR + r];
            float d0 = ev.x - zv0, d1 = ev.y - zv1, d2 = ev.z - zv2, d3 = ev.w - zv3;
            float4 o4;
            o4.x = zv0 + d0; o4.y = zv1 + d1; o4.z = zv2 + d2; o4.w = zv3 + d3;
            *(float4*)&out_zq[(size_t)(row0 + r) * ED + kq * 16 + 4 * m] = o4;
            sq += d0 * d0; sq += d1 * d1; sq += d2 * d2; sq += d3 * d3;
        }
        #pragma unroll
        for (int off = 32; off > 0; off >>= 1) sq += __shfl_down(sq, off, 64);
        int lane = t & 63, wv2 = t >> 6;
        if (lane == 0) warr[wv2] = sq;
    }
    __syncthreads();
    if (t == 0)
        ssep[blockIdx.x] = (warr[0] + warr[1]) + (warr[2] + warr[3]);
}

// ---------------------------------------------------------------------------
// k_final (R0 verbatim): deterministic combine of 512 SSE partials (double
// tree) and the 16x64 contrastive partials; writes the loss scalar.
__global__ __launch_bounds__(256) void k_final(const float* __restrict__ ssep,
                                               const float* __restrict__ cpart,
                                               float* __restrict__ out_loss) {
    __shared__ double SD[256];
    __shared__ float  CS;
    int t = threadIdx.x;
    SD[t] = (double)ssep[t] + (double)ssep[t + 256];
    __syncthreads();
    #pragma unroll
    for (int off = 128; off > 0; off >>= 1) {
        if (t < off) SD[t] += SD[t + off];
        __syncthreads();
    }
    if (t < 64) {
        float v = 0.0f;
        #pragma unroll
        for (int m = 0; m < 16; m++) v += cpart[m * 64 + t];
        float sq = v * v;
        #pragma unroll
        for (int off = 32; off > 0; off >>= 1) sq += __shfl_down(sq, off, 64);
        if (t == 0) CS = sq / (1024.0f * 1024.0f);
    }
    __syncthreads();
    if (t == 0) {
        float m = (float)(SD[0] / (double)ZTOT);
        float loss = m + 0.25f * m;         // LEGACY: mse + BETA*mse
        out_loss[0] = loss + CS;
    }
}

// ---------------------------------------------------------------------------
extern "C" void kernel_launch(void* const* d_in, const int* in_sizes, int n_in,
                              void* d_out, int out_size, void* d_ws, size_t ws_size,
                              hipStream_t stream) {
    (void)in_sizes; (void)n_in; (void)out_size; (void)ws_size;
    const float* z_     = (const float*)d_in[0];
    const float* conv_w = (const float*)d_in[1];
    const float* conv_b = (const float*)d_in[2];
    const float* emb    = (const float*)d_in[3];

    float* out      = (float*)d_out;
    float* out_zq   = out;
    float* out_loss = out + OFF_LOSS;
    float* out_samp = out + OFF_SAMP;
    float* out_idx  = out + OFF_IDX;

    char*  ws       = (char*)d_ws;
    float* wz       = (float*)ws;                         // 2M floats (8 MB)
    float* enorm    = (float*)(ws + 8388608);             // 1024 floats
    float* cpart    = (float*)(ws + 8392704);             // 16*64 floats
    float* ssep     = (float*)(ws + 8396800);             // 512 floats

    k_pre  <<<660, 256, 0, stream>>>(z_, conv_w, conv_b, wz, emb, out_samp, enorm, cpart);
    k_dist <<<512, 256, 0, stream>>>(wz, emb, enorm, out_idx, out_samp, out_zq, ssep);
    k_final<<<1,   256, 0, stream>>>(ssep, cpart, out_loss);
}